// Round 4
// baseline (93.523 us; speedup 1.0000x reference)
//
#include <hip/hip_runtime.h>

typedef __attribute__((ext_vector_type(8))) short short8;
typedef __attribute__((ext_vector_type(4))) float f32x4;

#define KPAD 40   // padded bf16 K-chunk row: 32 data + 8 pad (80B stride)

// workspace layout (bytes)
#define WS_HID   0u        // 256*256 f32      = 262144
#define WS_P     262144u   // 131072 f32       = 524288
#define WS_Z     786432u   // 1024 f32         = 4096
#define WS_CTX   790528u   // 256*256 f32      = 262144
#define WS_CTXP  1052672u  // 4*256*256 f32    = 1048576
#define WS_WBF   2101248u  // 8*256*40 bf16    = 163840 (ends 2265088)

__device__ __forceinline__ unsigned f2bfu(float f) {
    union { float f; unsigned u; } v; v.f = f;
    return (v.u + 0x7FFFu + ((v.u >> 16) & 1u)) >> 16;   // RNE
}
__device__ __forceinline__ float tanh_fast(float x) {
    float e2 = __expf(2.f * x);
    return 1.f - 2.f * __builtin_amdgcn_rcpf(e2 + 1.f);
}
__device__ __forceinline__ float sigmoid_fast(float x) {
    return __builtin_amdgcn_rcpf(1.f + __expf(-x));
}
__device__ __forceinline__ int4 pack8(float4 x0, float4 x1) {
    int4 q;
    q.x = (int)((f2bfu(x0.y) << 16) | f2bfu(x0.x));
    q.y = (int)((f2bfu(x0.w) << 16) | f2bfu(x0.z));
    q.z = (int)((f2bfu(x1.y) << 16) | f2bfu(x1.x));
    q.w = (int)((f2bfu(x1.w) << 16) | f2bfu(x1.z));
    return q;
}
__device__ __forceinline__ void gload16(const void* g, void* l) {
    __builtin_amdgcn_global_load_lds((const __attribute__((address_space(1))) void*)g,
                                     (__attribute__((address_space(3))) void*)l, 16, 0, 0);
}

// ---------------- K0: hid GEMV + W_i2h bf16 pre-chunking ----------------
__global__ __launch_bounds__(256) void k_prep(
    const float* __restrict__ prev_h, const float* __restrict__ W_i2h,
    const float* __restrict__ W_h2h, const float* __restrict__ b_h2h,
    float* __restrict__ hid, short* __restrict__ Wbf)
{
    int bid = blockIdx.x, tid = threadIdx.x;
    if (bid < 256) {                       // hid[b][h] = prev_h[b]·W_h2h[h] + b_h2h[h]
        __shared__ float ph[256];
        ph[tid] = prev_h[bid * 256 + tid];
        __syncthreads();
        float acc = b_h2h[tid];
        const float4* w = (const float4*)(W_h2h + tid * 256);
        #pragma unroll 8
        for (int k4 = 0; k4 < 64; ++k4) {
            float4 ww = w[k4];
            acc += ww.x * ph[k4*4+0] + ww.y * ph[k4*4+1] + ww.z * ph[k4*4+2] + ww.w * ph[k4*4+3];
        }
        hid[bid * 256 + tid] = acc;
    } else {                               // W_i2h -> bf16 chunks [8][256][40]
        int idx = (bid - 256) * 256 + tid;         // < 81920
        int kc = idx / (256 * KPAD);
        int rem = idx % (256 * KPAD);
        int n = rem / KPAD, kk = rem % KPAD;
        float v = (kk < 32) ? W_i2h[n * 256 + kc * 32 + kk] : 0.f;
        Wbf[idx] = (short)f2bfu(v);
    }
}

// ---------------- K1: fused e-score + exp + context partial ----------------
// 1024 blocks x 512 threads; tile 128 bt-rows x 256 h-cols; 8 waves (2 row x 4 col panels).
// A: reg-staged fp32->bf16 -> LDS dbuf. B: global_load_lds DMA (Wbf image == LDS image).
// Epilogue: e -> p=exp(e) (no max shift: |e| <= ||Wsc||_1 ~ 10), ctx partial from
// L2-hot re-read of this block's own A rows.
__global__ __launch_bounds__(512, 4) void k_escore_ctx(
    const float* __restrict__ BH, const short* __restrict__ Wbf,
    const float* __restrict__ hid, const float* __restrict__ Wsc,
    float* __restrict__ p_out, float* __restrict__ zbuf, float* __restrict__ ctxp)
{
    __shared__ char smem[64016];
    short* Al = (short*)smem;                   // [2][128][40] bf16 dbuf
    char*  BlB = smem + 20480;                  // [2][256][40] bf16 dbuf (DMA dest)
    short* Bl = (short*)BlB;
    float* eps = (float*)(smem + 61440);        // [4][128]
    float* pl  = (float*)(smem + 63488);        // [128]
    float* zw  = (float*)(smem + 64000);        // [2]

    const int tid = threadIdx.x;
    const int lane = tid & 63;
    const int w = tid >> 6;                     // 0..7
    const int wr = w >> 2, wc = w & 3;          // row-panel, col-panel
    const int l15 = lane & 15, lg = lane >> 4;
    const int bt0 = blockIdx.x * 128;
    const int b = bt0 >> 9;
    const int c = blockIdx.x & 3;

    const int arow = tid >> 2, akg = tid & 3;   // 128 rows x 4 k-groups
    const float* asrc = BH + (size_t)(bt0 + arow) * 256 + akg * 8;
    const int nslot = (w < 4) ? 3 : 2;          // 20 x 1KB B-slots over 8 waves

    f32x4 acc[4][4];
    #pragma unroll
    for (int i = 0; i < 4; i++)
        #pragma unroll
        for (int j = 0; j < 4; j++) acc[i][j] = (f32x4){0.f, 0.f, 0.f, 0.f};

    auto stage = [&](int kc) {
        int bu = kc & 1;
        // A: global fp32 loads (issued first, stay in flight)
        float4 x0 = *(const float4*)(asrc + kc * 32);
        float4 x1 = *(const float4*)(asrc + kc * 32 + 4);
        // B: DMA Wbf chunk kc (20KB, identical layout) into LDS
        const char* gsb = (const char*)Wbf + (size_t)kc * 20480 + lane * 16;
        char* lsb = BlB + bu * 20480;
        #pragma unroll
        for (int i = 0; i < 3; ++i)
            if (i < nslot) {
                int slot = w + 8 * i;
                gload16(gsb + slot * 1024, lsb + slot * 1024);
            }
        // A: convert + LDS write
        *(int4*)&Al[bu * 5120 + arow * KPAD + akg * 8] = pack8(x0, x1);
    };

    stage(0);
    __syncthreads();

    #pragma unroll
    for (int ks = 0; ks < 8; ++ks) {
        const int cur = ks & 1;
        short8 af[4], bfr[4];
        #pragma unroll
        for (int rf = 0; rf < 4; rf++)
            af[rf] = *(const short8*)&Al[cur * 5120 + (wr * 64 + rf * 16 + l15) * KPAD + lg * 8];
        #pragma unroll
        for (int cf = 0; cf < 4; cf++)
            bfr[cf] = *(const short8*)&Bl[cur * 10240 + (wc * 64 + cf * 16 + l15) * KPAD + lg * 8];
        if (ks < 7) stage(ks + 1);
        #pragma unroll
        for (int rf = 0; rf < 4; rf++)
            #pragma unroll
            for (int cf = 0; cf < 4; cf++)
                acc[rf][cf] = __builtin_amdgcn_mfma_f32_16x16x32_bf16(af[rf], bfr[cf], acc[rf][cf], 0, 0, 0);
        __syncthreads();
    }

    // ---- e partials over this wave's 64 cols ----
    float esum[4][4];
    #pragma unroll
    for (int rf = 0; rf < 4; rf++)
        #pragma unroll
        for (int r = 0; r < 4; r++) esum[rf][r] = 0.f;

    #pragma unroll
    for (int cf = 0; cf < 4; cf++) {
        int col = wc * 64 + cf * 16 + l15;
        float wsv = Wsc[col];
        float hd = hid[b * 256 + col];
        #pragma unroll
        for (int rf = 0; rf < 4; rf++)
            #pragma unroll
            for (int r = 0; r < 4; r++)
                esum[rf][r] += wsv * tanh_fast(acc[rf][cf][r] + hd);
    }
    #pragma unroll
    for (int rf = 0; rf < 4; rf++)
        #pragma unroll
        for (int r = 0; r < 4; r++) {
            float s = esum[rf][r];
            s += __shfl_xor(s, 1); s += __shfl_xor(s, 2);
            s += __shfl_xor(s, 4); s += __shfl_xor(s, 8);
            esum[rf][r] = s;
        }
    if (l15 == 0) {
        #pragma unroll
        for (int rf = 0; rf < 4; rf++)
            #pragma unroll
            for (int r = 0; r < 4; r++)
                eps[wc * 128 + wr * 64 + rf * 16 + lg * 4 + r] = esum[rf][r];
    }
    __syncthreads();

    // ---- p = exp(e), z partial ----
    if (tid < 128) {
        float e = eps[tid] + eps[128 + tid] + eps[256 + tid] + eps[384 + tid];
        float p = __expf(e);          // |e| <= ||Wsc||_1 ~ 10.2: no overflow; softmax shift-invariant
        p_out[bt0 + tid] = p;
        pl[tid] = p;
        float z = p;
        z += __shfl_xor(z, 1); z += __shfl_xor(z, 2); z += __shfl_xor(z, 4);
        z += __shfl_xor(z, 8); z += __shfl_xor(z, 16); z += __shfl_xor(z, 32);
        if ((tid & 63) == 0) zw[tid >> 6] = z;
    }
    __syncthreads();

    if (tid == 0) zbuf[blockIdx.x] = zw[0] + zw[1];

    // ---- ctx partial: re-read own A rows (L2-hot), weight by p ----
    float* r2 = (float*)smem;                   // overlay dead A dbuf: [2][256]
    {
        int d = tid & 255, rh = tid >> 8;       // rh: 0/1 half of 128 rows
        const float* bh = BH + (size_t)(bt0 + rh * 64) * 256 + d;
        float accv = 0.f;
        #pragma unroll 8
        for (int t = 0; t < 64; ++t) accv += pl[rh * 64 + t] * bh[(size_t)t * 256];
        r2[rh * 256 + d] = accv;
    }
    __syncthreads();
    if (tid < 256)
        ctxp[((size_t)(c * 256 + b)) * 256 + tid] = r2[tid] + r2[256 + tid];
}

// ---------------- K2: finalize alpha + ctx ----------------
__global__ __launch_bounds__(256) void k_finalize(
    const float* __restrict__ p, const float* __restrict__ zbuf,
    const float* __restrict__ ctxp, float* __restrict__ alpha, float* __restrict__ ctx)
{
    int b = blockIdx.x, t = threadIdx.x;
    float Z = zbuf[b * 4 + 0] + zbuf[b * 4 + 1] + zbuf[b * 4 + 2] + zbuf[b * 4 + 3];
    float inv = 1.f / Z;
    alpha[b * 512 + t] = p[b * 512 + t] * inv;
    alpha[b * 512 + 256 + t] = p[b * 512 + 256 + t] * inv;
    float s = 0.f;
    #pragma unroll
    for (int cc = 0; cc < 4; ++cc) s += ctxp[((size_t)(cc * 256 + b)) * 256 + t];
    ctx[b * 256 + t] = s * inv;
}

// ---------------- K3: gates GEMM (256x1024, K=608=19x32) fused with LSTM ----------------
__global__ __launch_bounds__(256) void k_gates_lstm(
    const float* __restrict__ ctx, const float* __restrict__ onehot,
    const float* __restrict__ prev_h, const float* __restrict__ W_ih,
    const float* __restrict__ W_hh, const float* __restrict__ b_ih,
    const float* __restrict__ b_hh, const float* __restrict__ prev_c,
    float* __restrict__ out)
{
    __shared__ char smem[20800];
    short* AlB = (short*)smem;            // [2][64*KPAD]
    short* BlB = (short*)smem + 5120;     // [2][64*KPAD]
    const int tid = threadIdx.x;
    const int lane = tid & 63;
    const int w = tid >> 6;
    const int l15 = lane & 15, lg = lane >> 4;
    const int rb = blockIdx.x * 64;       // row base (batch)
    const int hb = blockIdx.y;            // col-block: n' in [hb*64, hb*64+64)

    f32x4 acc[4];
    #pragma unroll
    for (int j = 0; j < 4; j++) acc[j] = (f32x4){0.f, 0.f, 0.f, 0.f};

    const int arow = tid >> 2, akg = tid & 3;
    const int rg = rb + arow;
    const int bn = tid >> 2, bq = tid & 3;
    const int np_ = hb * 64 + bn, hh_ = np_ >> 2, gg_ = np_ & 3;
    const float* wih_row = W_ih + (size_t)(gg_ * 256 + hh_) * 352;
    const float* whh_row = W_hh + (size_t)(gg_ * 256 + hh_) * 256;

    auto stageAB = [&](int kc, int bu) {
        int k0 = kc * 32 + akg * 8;
        const float4* pa;
        if (k0 < 256)      pa = (const float4*)(ctx    + rg * 256 + k0);
        else if (k0 < 352) pa = (const float4*)(onehot + rg * 96  + (k0 - 256));
        else               pa = (const float4*)(prev_h + rg * 256 + (k0 - 352));
        float4 x0 = pa[0], x1 = pa[1];
        *(int4*)&AlB[bu * 2560 + arow * KPAD + akg * 8] = pack8(x0, x1);
        int kb = kc * 32 + bq * 8;
        const float* pb = (kb < 352) ? (wih_row + kb) : (whh_row + (kb - 352));
        float4 y0 = *(const float4*)pb, y1 = *(const float4*)(pb + 4);
        *(int4*)&BlB[bu * 2560 + bn * KPAD + bq * 8] = pack8(y0, y1);
    };

    stageAB(0, 0);
    __syncthreads();

    for (int kc = 0; kc < 19; ++kc) {
        int cur = kc & 1;
        short8 af = *(const short8*)&AlB[cur * 2560 + (w * 16 + l15) * KPAD + lg * 8];
        short8 bfr[4];
        #pragma unroll
        for (int cf = 0; cf < 4; cf++)
            bfr[cf] = *(const short8*)&BlB[cur * 2560 + (cf * 16 + l15) * KPAD + lg * 8];
        if (kc < 18) stageAB(kc + 1, cur ^ 1);
        #pragma unroll
        for (int cf = 0; cf < 4; cf++)
            acc[cf] = __builtin_amdgcn_mfma_f32_16x16x32_bf16(af, bfr[cf], acc[cf], 0, 0, 0);
        __syncthreads();
    }

    float* Gt = (float*)smem;                    // [64][65]
    #pragma unroll
    for (int cf = 0; cf < 4; cf++) {
        int col = cf * 16 + l15;
        int np = hb * 64 + col;
        int hg = np >> 2, g = np & 3;
        float bias = b_ih[g * 256 + hg] + b_hh[g * 256 + hg];
        #pragma unroll
        for (int r = 0; r < 4; r++)
            Gt[(w * 16 + lg * 4 + r) * 65 + col] = acc[cf][r] + bias;
    }
    __syncthreads();

    #pragma unroll
    for (int it = 0; it < 4; ++it) {
        int elem = it * 256 + tid;               // < 1024
        int row = elem >> 4, hl = elem & 15;
        float gi = Gt[row * 65 + hl * 4 + 0];
        float gf = Gt[row * 65 + hl * 4 + 1];
        float gg = Gt[row * 65 + hl * 4 + 2];
        float go = Gt[row * 65 + hl * 4 + 3];
        int bg = rb + row, hglob = hb * 16 + hl;
        float cv = sigmoid_fast(gf) * prev_c[bg * 256 + hglob] + sigmoid_fast(gi) * tanh_fast(gg);
        out[bg * 256 + hglob] = sigmoid_fast(go) * tanh_fast(cv);
        out[65536 + bg * 256 + hglob] = cv;
    }
}

extern "C" void kernel_launch(void* const* d_in, const int* in_sizes, int n_in,
                              void* d_out, int out_size, void* d_ws, size_t ws_size,
                              hipStream_t stream) {
    (void)in_sizes; (void)n_in; (void)out_size; (void)ws_size;
    const float* prev_h  = (const float*)d_in[0];
    const float* prev_c  = (const float*)d_in[1];
    const float* batch_H = (const float*)d_in[2];
    const float* onehot  = (const float*)d_in[3];
    const float* W_i2h   = (const float*)d_in[4];
    const float* W_h2h   = (const float*)d_in[5];
    const float* b_h2h   = (const float*)d_in[6];
    const float* W_score = (const float*)d_in[7];
    const float* W_ih    = (const float*)d_in[8];
    const float* W_hh    = (const float*)d_in[9];
    const float* b_ih    = (const float*)d_in[10];
    const float* b_hh    = (const float*)d_in[11];

    char* ws = (char*)d_ws;
    float* hid   = (float*)(ws + WS_HID);
    float* p     = (float*)(ws + WS_P);
    float* zbuf  = (float*)(ws + WS_Z);
    float* ctx   = (float*)(ws + WS_CTX);
    float* ctxp  = (float*)(ws + WS_CTXP);
    short* Wbf   = (short*)(ws + WS_WBF);

    float* out = (float*)d_out;
    float* alpha = out + 131072;            // h:[0,64K) c:[64K,128K) alpha:[128K,256K) floats

    hipLaunchKernelGGL(k_prep,       dim3(576),    dim3(256), 0, stream,
                       prev_h, W_i2h, W_h2h, b_h2h, hid, Wbf);
    hipLaunchKernelGGL(k_escore_ctx, dim3(1024),   dim3(512), 0, stream,
                       batch_H, Wbf, hid, W_score, p, zbuf, ctxp);
    hipLaunchKernelGGL(k_finalize,   dim3(256),    dim3(256), 0, stream,
                       p, zbuf, ctxp, alpha, ctx);
    hipLaunchKernelGGL(k_gates_lstm, dim3(4, 16),  dim3(256), 0, stream,
                       ctx, onehot, prev_h, W_ih, W_hh, b_ih, b_hh, prev_c, out);
}

// Round 5
// 82.539 us; speedup vs baseline: 1.1331x; 1.1331x over previous
//
#include <hip/hip_runtime.h>

typedef __attribute__((ext_vector_type(8))) short short8;
typedef __attribute__((ext_vector_type(4))) float f32x4;

#define KPAD 40   // padded bf16 K-chunk row: 32 data + 8 pad (80B stride)

// workspace layout (bytes)
#define WS_HID   0u        // 256*256 f32      = 262144
#define WS_P     262144u   // 131072 f32       = 524288
#define WS_Z     786432u   // 1024 f32         = 4096
#define WS_CTX   790528u   // 256*256 f32      = 262144
#define WS_CTXP  1052672u  // 4*256*256 f32    = 1048576
#define WS_WBF   2101248u  // 8*256*40 bf16    = 163840 (ends 2265088)

__device__ __forceinline__ unsigned f2bfu(float f) {
    union { float f; unsigned u; } v; v.f = f;
    return (v.u + 0x7FFFu + ((v.u >> 16) & 1u)) >> 16;   // RNE
}
__device__ __forceinline__ float tanh_fast(float x) {
    float e2 = __expf(2.f * x);
    return 1.f - 2.f * __builtin_amdgcn_rcpf(e2 + 1.f);
}
__device__ __forceinline__ float sigmoid_fast(float x) {
    return __builtin_amdgcn_rcpf(1.f + __expf(-x));
}
__device__ __forceinline__ int4 pack8(float4 x0, float4 x1) {
    int4 q;
    q.x = (int)((f2bfu(x0.y) << 16) | f2bfu(x0.x));
    q.y = (int)((f2bfu(x0.w) << 16) | f2bfu(x0.z));
    q.z = (int)((f2bfu(x1.y) << 16) | f2bfu(x1.x));
    q.w = (int)((f2bfu(x1.w) << 16) | f2bfu(x1.z));
    return q;
}
__device__ __forceinline__ void gload16(const void* g, void* l) {
    __builtin_amdgcn_global_load_lds((const __attribute__((address_space(1))) void*)g,
                                     (__attribute__((address_space(3))) void*)l, 16, 0, 0);
}

// ---------------- K0: hid GEMV + W_i2h bf16 pre-chunking ----------------
__global__ __launch_bounds__(256) void k_prep(
    const float* __restrict__ prev_h, const float* __restrict__ W_i2h,
    const float* __restrict__ W_h2h, const float* __restrict__ b_h2h,
    float* __restrict__ hid, short* __restrict__ Wbf)
{
    int bid = blockIdx.x, tid = threadIdx.x;
    if (bid < 256) {                       // hid[b][h] = prev_h[b]·W_h2h[h] + b_h2h[h]
        __shared__ float ph[256];
        ph[tid] = prev_h[bid * 256 + tid];
        __syncthreads();
        float acc = b_h2h[tid];
        const float4* w = (const float4*)(W_h2h + tid * 256);
        #pragma unroll 8
        for (int k4 = 0; k4 < 64; ++k4) {
            float4 ww = w[k4];
            acc += ww.x * ph[k4*4+0] + ww.y * ph[k4*4+1] + ww.z * ph[k4*4+2] + ww.w * ph[k4*4+3];
        }
        hid[bid * 256 + tid] = acc;
    } else {                               // W_i2h -> bf16 chunks [8][256][40]
        int idx = (bid - 256) * 256 + tid;         // < 81920
        int kc = idx / (256 * KPAD);
        int rem = idx % (256 * KPAD);
        int n = rem / KPAD, kk = rem % KPAD;
        float v = (kk < 32) ? W_i2h[n * 256 + kc * 32 + kk] : 0.f;
        Wbf[idx] = (short)f2bfu(v);
    }
}

// ---------------- K1: fused e-score + exp + context partial ----------------
// 1024 blocks x 1024 threads (16 waves); tile 128 bt-rows x 256 h-cols;
// wave-tile 64x32 (2 row-panels x 8 col-panels) -> acc 32 VGPR, ~95 total, no spill.
// A: reg-staged fp32->bf16 -> LDS dbuf. B: global_load_lds DMA of pre-chunked Wbf.
// Epilogue: p=exp(e) (|e| <= ||Wsc||_1 ~ 10, shift-free), ctx partial via L3 re-read.
__global__ __launch_bounds__(1024, 4) void k_escore_ctx(
    const float* __restrict__ BH, const short* __restrict__ Wbf,
    const float* __restrict__ hid, const float* __restrict__ Wsc,
    float* __restrict__ p_out, float* __restrict__ zbuf, float* __restrict__ ctxp)
{
    __shared__ char smem[61448];
    short* Al = (short*)smem;                   // [2][128][40] bf16 dbuf (20480 B)
    char*  BlB = smem + 20480;                  // [2][256][40] bf16 dbuf, DMA dest (40960 B)
    short* Bl = (short*)BlB;
    // epilogue overlays (A region dead after K-loop):
    float* eps = (float*)smem;                  // [8][128]  4096 B
    float* pl  = (float*)(smem + 4096);         // [128]
    float* r4  = (float*)(smem + 4608);         // [4][256]  4096 B
    float* zw  = (float*)(smem + 61440);        // [2]

    const int tid = threadIdx.x;
    const int lane = tid & 63;
    const int w = tid >> 6;                     // 0..15
    const int rp = w >> 3, cp = w & 7;          // row-panel(2) x col-panel(8)
    const int l15 = lane & 15, lg = lane >> 4;
    const int bt0 = blockIdx.x * 128;
    const int b = bt0 >> 9;
    const int c = blockIdx.x & 3;

    const int arow = tid >> 3, akg = tid & 7;   // 128 rows x 8 k-quads
    const float* asrc = BH + (size_t)(bt0 + arow) * 256 + akg * 4;
    const int nslot = (w < 4) ? 2 : 1;          // 20 x 1KB B-slots over 16 waves

    f32x4 acc[4][2];
    #pragma unroll
    for (int i = 0; i < 4; i++)
        #pragma unroll
        for (int j = 0; j < 2; j++) acc[i][j] = (f32x4){0.f, 0.f, 0.f, 0.f};

    auto stage = [&](int kc) {
        int bu = kc & 1;
        // A: one float4 per thread (issued first, stays ahead of DMAs)
        float4 x0 = *(const float4*)(asrc + kc * 32);
        // B: DMA Wbf chunk kc (20KB, identical layout) into LDS
        const char* gsb = (const char*)Wbf + (size_t)kc * 20480 + lane * 16;
        char* lsb = BlB + bu * 20480;
        #pragma unroll
        for (int i = 0; i < 2; ++i)
            if (i < nslot) {
                int slot = w + 16 * i;
                gload16(gsb + slot * 1024, lsb + slot * 1024);
            }
        // A: convert + 8B LDS write
        int2 q;
        q.x = (int)((f2bfu(x0.y) << 16) | f2bfu(x0.x));
        q.y = (int)((f2bfu(x0.w) << 16) | f2bfu(x0.z));
        *(int2*)&Al[bu * 5120 + arow * KPAD + akg * 4] = q;
    };

    stage(0);
    __syncthreads();

    #pragma unroll
    for (int ks = 0; ks < 8; ++ks) {
        const int cur = ks & 1;
        short8 af[4], bfr[2];
        #pragma unroll
        for (int rf = 0; rf < 4; rf++)
            af[rf] = *(const short8*)&Al[cur * 5120 + (rp * 64 + rf * 16 + l15) * KPAD + lg * 8];
        #pragma unroll
        for (int cf = 0; cf < 2; cf++)
            bfr[cf] = *(const short8*)&Bl[cur * 10240 + (cp * 32 + cf * 16 + l15) * KPAD + lg * 8];
        if (ks < 7) stage(ks + 1);
        #pragma unroll
        for (int rf = 0; rf < 4; rf++)
            #pragma unroll
            for (int cf = 0; cf < 2; cf++)
                acc[rf][cf] = __builtin_amdgcn_mfma_f32_16x16x32_bf16(af[rf], bfr[cf], acc[rf][cf], 0, 0, 0);
        __syncthreads();
    }

    // ---- e partials over this wave's 32 cols ----
    float esum[4][4];
    #pragma unroll
    for (int rf = 0; rf < 4; rf++)
        #pragma unroll
        for (int r = 0; r < 4; r++) esum[rf][r] = 0.f;

    #pragma unroll
    for (int cf = 0; cf < 2; cf++) {
        int col = cp * 32 + cf * 16 + l15;
        float wsv = Wsc[col];
        float hd = hid[b * 256 + col];
        #pragma unroll
        for (int rf = 0; rf < 4; rf++)
            #pragma unroll
            for (int r = 0; r < 4; r++)
                esum[rf][r] += wsv * tanh_fast(acc[rf][cf][r] + hd);
    }
    #pragma unroll
    for (int rf = 0; rf < 4; rf++)
        #pragma unroll
        for (int r = 0; r < 4; r++) {
            float s = esum[rf][r];
            s += __shfl_xor(s, 1); s += __shfl_xor(s, 2);
            s += __shfl_xor(s, 4); s += __shfl_xor(s, 8);
            esum[rf][r] = s;
        }
    if (l15 == 0) {
        #pragma unroll
        for (int rf = 0; rf < 4; rf++)
            #pragma unroll
            for (int r = 0; r < 4; r++)
                eps[cp * 128 + rp * 64 + rf * 16 + lg * 4 + r] = esum[rf][r];
    }
    __syncthreads();

    // ---- p = exp(e), z partial ----
    if (tid < 128) {
        float e = 0.f;
        #pragma unroll
        for (int g = 0; g < 8; ++g) e += eps[g * 128 + tid];
        float p = __expf(e);          // |e| <= ||Wsc||_1 ~ 10.2: no overflow; softmax shift-invariant
        p_out[bt0 + tid] = p;
        pl[tid] = p;
        float z = p;
        z += __shfl_xor(z, 1); z += __shfl_xor(z, 2); z += __shfl_xor(z, 4);
        z += __shfl_xor(z, 8); z += __shfl_xor(z, 16); z += __shfl_xor(z, 32);
        if ((tid & 63) == 0) zw[tid >> 6] = z;
    }
    __syncthreads();

    if (tid == 0) zbuf[blockIdx.x] = zw[0] + zw[1];

    // ---- ctx partial: re-read own A rows (L2/L3-hot), weight by p ----
    {
        int d = tid & 255, rh = tid >> 8;       // rh: quarter of 128 rows
        const float* bh = BH + (size_t)(bt0 + rh * 32) * 256 + d;
        float accv = 0.f;
        #pragma unroll 8
        for (int t = 0; t < 32; ++t) accv += pl[rh * 32 + t] * bh[(size_t)t * 256];
        r4[rh * 256 + d] = accv;
    }
    __syncthreads();
    if (tid < 256)
        ctxp[((size_t)(c * 256 + b)) * 256 + tid] = r4[tid] + r4[256 + tid] + r4[512 + tid] + r4[768 + tid];
}

// ---------------- K2: finalize alpha + ctx ----------------
__global__ __launch_bounds__(256) void k_finalize(
    const float* __restrict__ p, const float* __restrict__ zbuf,
    const float* __restrict__ ctxp, float* __restrict__ alpha, float* __restrict__ ctx)
{
    int b = blockIdx.x, t = threadIdx.x;
    float Z = zbuf[b * 4 + 0] + zbuf[b * 4 + 1] + zbuf[b * 4 + 2] + zbuf[b * 4 + 3];
    float inv = 1.f / Z;
    alpha[b * 512 + t] = p[b * 512 + t] * inv;
    alpha[b * 512 + 256 + t] = p[b * 512 + 256 + t] * inv;
    float s = 0.f;
    #pragma unroll
    for (int cc = 0; cc < 4; ++cc) s += ctxp[((size_t)(cc * 256 + b)) * 256 + t];
    ctx[b * 256 + t] = s * inv;
}

// ---------------- K3: gates GEMM (256x1024, K=608=19x32) fused with LSTM ----------------
__global__ __launch_bounds__(256) void k_gates_lstm(
    const float* __restrict__ ctx, const float* __restrict__ onehot,
    const float* __restrict__ prev_h, const float* __restrict__ W_ih,
    const float* __restrict__ W_hh, const float* __restrict__ b_ih,
    const float* __restrict__ b_hh, const float* __restrict__ prev_c,
    float* __restrict__ out)
{
    __shared__ char smem[20800];
    short* AlB = (short*)smem;            // [2][64*KPAD]
    short* BlB = (short*)smem + 5120;     // [2][64*KPAD]
    const int tid = threadIdx.x;
    const int lane = tid & 63;
    const int w = tid >> 6;
    const int l15 = lane & 15, lg = lane >> 4;
    const int rb = blockIdx.x * 64;       // row base (batch)
    const int hb = blockIdx.y;            // col-block: n' in [hb*64, hb*64+64)

    f32x4 acc[4];
    #pragma unroll
    for (int j = 0; j < 4; j++) acc[j] = (f32x4){0.f, 0.f, 0.f, 0.f};

    const int arow = tid >> 2, akg = tid & 3;
    const int rg = rb + arow;
    const int bn = tid >> 2, bq = tid & 3;
    const int np_ = hb * 64 + bn, hh_ = np_ >> 2, gg_ = np_ & 3;
    const float* wih_row = W_ih + (size_t)(gg_ * 256 + hh_) * 352;
    const float* whh_row = W_hh + (size_t)(gg_ * 256 + hh_) * 256;

    auto stageAB = [&](int kc, int bu) {
        int k0 = kc * 32 + akg * 8;
        const float4* pa;
        if (k0 < 256)      pa = (const float4*)(ctx    + rg * 256 + k0);
        else if (k0 < 352) pa = (const float4*)(onehot + rg * 96  + (k0 - 256));
        else               pa = (const float4*)(prev_h + rg * 256 + (k0 - 352));
        float4 x0 = pa[0], x1 = pa[1];
        *(int4*)&AlB[bu * 2560 + arow * KPAD + akg * 8] = pack8(x0, x1);
        int kb = kc * 32 + bq * 8;
        const float* pb = (kb < 352) ? (wih_row + kb) : (whh_row + (kb - 352));
        float4 y0 = *(const float4*)pb, y1 = *(const float4*)(pb + 4);
        *(int4*)&BlB[bu * 2560 + bn * KPAD + bq * 8] = pack8(y0, y1);
    };

    stageAB(0, 0);
    __syncthreads();

    for (int kc = 0; kc < 19; ++kc) {
        int cur = kc & 1;
        short8 af = *(const short8*)&AlB[cur * 2560 + (w * 16 + l15) * KPAD + lg * 8];
        short8 bfr[4];
        #pragma unroll
        for (int cf = 0; cf < 4; cf++)
            bfr[cf] = *(const short8*)&BlB[cur * 2560 + (cf * 16 + l15) * KPAD + lg * 8];
        if (kc < 18) stageAB(kc + 1, cur ^ 1);
        #pragma unroll
        for (int cf = 0; cf < 4; cf++)
            acc[cf] = __builtin_amdgcn_mfma_f32_16x16x32_bf16(af, bfr[cf], acc[cf], 0, 0, 0);
        __syncthreads();
    }

    float* Gt = (float*)smem;                    // [64][65]
    #pragma unroll
    for (int cf = 0; cf < 4; cf++) {
        int col = cf * 16 + l15;
        int np = hb * 64 + col;
        int hg = np >> 2, g = np & 3;
        float bias = b_ih[g * 256 + hg] + b_hh[g * 256 + hg];
        #pragma unroll
        for (int r = 0; r < 4; r++)
            Gt[(w * 16 + lg * 4 + r) * 65 + col] = acc[cf][r] + bias;
    }
    __syncthreads();

    #pragma unroll
    for (int it = 0; it < 4; ++it) {
        int elem = it * 256 + tid;               // < 1024
        int row = elem >> 4, hl = elem & 15;
        float gi = Gt[row * 65 + hl * 4 + 0];
        float gf = Gt[row * 65 + hl * 4 + 1];
        float gg = Gt[row * 65 + hl * 4 + 2];
        float go = Gt[row * 65 + hl * 4 + 3];
        int bg = rb + row, hglob = hb * 16 + hl;
        float cv = sigmoid_fast(gf) * prev_c[bg * 256 + hglob] + sigmoid_fast(gi) * tanh_fast(gg);
        out[bg * 256 + hglob] = sigmoid_fast(go) * tanh_fast(cv);
        out[65536 + bg * 256 + hglob] = cv;
    }
}

extern "C" void kernel_launch(void* const* d_in, const int* in_sizes, int n_in,
                              void* d_out, int out_size, void* d_ws, size_t ws_size,
                              hipStream_t stream) {
    (void)in_sizes; (void)n_in; (void)out_size; (void)ws_size;
    const float* prev_h  = (const float*)d_in[0];
    const float* prev_c  = (const float*)d_in[1];
    const float* batch_H = (const float*)d_in[2];
    const float* onehot  = (const float*)d_in[3];
    const float* W_i2h   = (const float*)d_in[4];
    const float* W_h2h   = (const float*)d_in[5];
    const float* b_h2h   = (const float*)d_in[6];
    const float* W_score = (const float*)d_in[7];
    const float* W_ih    = (const float*)d_in[8];
    const float* W_hh    = (const float*)d_in[9];
    const float* b_ih    = (const float*)d_in[10];
    const float* b_hh    = (const float*)d_in[11];

    char* ws = (char*)d_ws;
    float* hid   = (float*)(ws + WS_HID);
    float* p     = (float*)(ws + WS_P);
    float* zbuf  = (float*)(ws + WS_Z);
    float* ctx   = (float*)(ws + WS_CTX);
    float* ctxp  = (float*)(ws + WS_CTXP);
    short* Wbf   = (short*)(ws + WS_WBF);

    float* out = (float*)d_out;
    float* alpha = out + 131072;            // h:[0,64K) c:[64K,128K) alpha:[128K,256K) floats

    hipLaunchKernelGGL(k_prep,       dim3(576),    dim3(256),  0, stream,
                       prev_h, W_i2h, W_h2h, b_h2h, hid, Wbf);
    hipLaunchKernelGGL(k_escore_ctx, dim3(1024),   dim3(1024), 0, stream,
                       batch_H, Wbf, hid, W_score, p, zbuf, ctxp);
    hipLaunchKernelGGL(k_finalize,   dim3(256),    dim3(256),  0, stream,
                       p, zbuf, ctxp, alpha, ctx);
    hipLaunchKernelGGL(k_gates_lstm, dim3(4, 16),  dim3(256),  0, stream,
                       ctx, onehot, prev_h, W_ih, W_hh, b_ih, b_hh, prev_c, out);
}